// Round 2
// baseline (25867.902 us; speedup 1.0000x reference)
//
#include <hip/hip_runtime.h>
#include <cstdint>
#include <cstddef>

typedef __attribute__((ext_vector_type(8))) short bf16x8;
typedef __attribute__((ext_vector_type(4))) float f32x4;
#define DEVI __device__ __forceinline__

constexpr int B = 256, S = 128, V = 128, C = 16, H = 1024, Z = 256, NSTEP = 128;
constexpr int VC = V * C, G3 = 3 * H;

typedef __attribute__((address_space(1))) const unsigned short* gas_p;
typedef __attribute__((address_space(3))) unsigned short* las_p;

DEVI unsigned short f2bf(float f){unsigned u=__float_as_uint(f);u+=0x7fffu+((u>>16)&1u);return (unsigned short)(u>>16);}
DEVI float sigm(float x){return 1.f/(1.f+expf(-x));}
DEVI f32x4 MFMA(bf16x8 a,bf16x8 b,f32x4 c){return __builtin_amdgcn_mfma_f32_16x16x32_bf16(a,b,c,0,0,0);}
DEVI void stage16(const unsigned short* g, unsigned short* l){__builtin_amdgcn_global_load_lds((gas_p)g,(las_p)l,16,0,0);}

// monotonic-counter grid barrier: release add, relaxed spin, acquire fence.
DEVI void gbar(unsigned* cnt, unsigned nblk, unsigned& tgt){
  __syncthreads();
  if (threadIdx.x==0){
    tgt += nblk;
    __threadfence();                       // release prior writes (wb L2)
    __hip_atomic_fetch_add(cnt,1u,__ATOMIC_RELEASE,__HIP_MEMORY_SCOPE_AGENT);
    while (__hip_atomic_load(cnt,__ATOMIC_RELAXED,__HIP_MEMORY_SCOPE_AGENT) < tgt)
      __builtin_amdgcn_s_sleep(1);
    __threadfence();                       // acquire (inv L1/L2)
  }
  __syncthreads();
}

// ---------------- prep kernels ----------------
__global__ void k_cvt(const float* __restrict__ src, unsigned short* __restrict__ dst, int n){
  for (int i=blockIdx.x*256+threadIdx.x;i<n;i+=gridDim.x*256) dst[i]=f2bf(src[i]);
}

// x (B,V,S) -> xtb (S, B*V) bf16
__global__ void k_xt(const float* __restrict__ x, unsigned short* __restrict__ xtb){
  __shared__ float tile[32][33];
  int sb=blockIdx.x*32, rb=blockIdx.y*32, tx=threadIdx.x, ty=threadIdx.y;
  for (int i=ty;i<32;i+=8) tile[i][tx]=x[(size_t)(rb+i)*S+sb+tx];
  __syncthreads();
  for (int i=ty;i<32;i+=8) xtb[(size_t)(sb+i)*(B*V)+rb+tx]=f2bf(tile[tx][i]);
}

// c1_Wih (G3, VC+Z) cols [0,VC) -> WT (VC, G3)
__global__ void k_wt(const float* __restrict__ w, float* __restrict__ wt){
  __shared__ float tile[32][33];
  int vb=blockIdx.x*32, nb=blockIdx.y*32, tx=threadIdx.x, ty=threadIdx.y;
  for (int i=ty;i<32;i+=8) tile[i][tx]=w[(size_t)(nb+i)*(VC+Z)+vb+tx];
  __syncthreads();
  for (int i=ty;i<32;i+=8) wt[(size_t)(vb+i)*G3+nb+tx]=tile[tx][i];
}

__global__ __launch_bounds__(256) void k_mu_var_z(const float* __restrict__ hf,const float* __restrict__ hb,
    const float* __restrict__ Wmu,const float* __restrict__ bmu,
    const float* __restrict__ Wvar,const float* __restrict__ bvar,
    const float* __restrict__ noise,
    float* __restrict__ omu,float* __restrict__ ovar,float* __restrict__ oz,float* __restrict__ zws){
  __shared__ float e[2*H];
  int b=blockIdx.x, t=threadIdx.x;
  for (int i=0;i<2*H/256;++i){int k=t+i*256; e[k]=(k<H)?hf[b*H+k]:hb[b*H+k-H];}
  __syncthreads();
  const float* wm=Wmu+(size_t)t*2*H; const float* wv=Wvar+(size_t)t*2*H;
  float am=bmu[t], av=bvar[t];
  for (int k=0;k<2*H;++k){am+=e[k]*wm[k];av+=e[k]*wv[k];}
  float vv=expf(av), zz=am+vv*noise[b*Z+t];
  omu[b*Z+t]=am; ovar[b*Z+t]=vv; oz[b*Z+t]=zz; zws[b*Z+t]=zz;
}

__global__ void k_zpart(const float* __restrict__ z,const float* __restrict__ c1Wih,
                        const float* __restrict__ bih,float* __restrict__ zpart){
  int idx=blockIdx.x*256+threadIdx.x;
  int b=idx/G3, n=idx%G3;
  const float* w=c1Wih+(size_t)n*(VC+Z)+VC;
  const float* zr=z+b*Z;
  float a=bih[n];
  for (int k=0;k<Z;++k) a+=zr[k]*w[k];
  zpart[idx]=a;
}

__global__ void k_h1init(const float* __restrict__ z,const float* __restrict__ Winit,
                         const float* __restrict__ binit,
                         float* __restrict__ h1f,unsigned short* __restrict__ h1b,int* __restrict__ idxb){
  int idx=blockIdx.x*256+threadIdx.x;
  int b=idx>>10, jj=idx&(H-1);
  const float* w=Winit+(size_t)jj*Z;
  const float* zr=z+b*Z;
  float a=binit[jj];
  for (int k=0;k<Z;++k) a+=zr[k]*w[k];
  float t=tanhf(a);
  h1f[idx]=t; h1b[idx]=f2bf(t);
  if (idx<B) idxb[idx]=VC-1;
}

// ---------------- persistent encoder ----------------
struct EncP {
  const unsigned short *xtb,*wihf,*whhf,*wihb,*whhb;
  const float *bihf,*bhhf,*bihb,*bhhb;
  unsigned short *hfb0,*hfb1,*hbb0,*hbb1;
  float *hf,*hb;
  unsigned* bar;
};

__global__ __launch_bounds__(256,1) void k_enc(EncP P){
  const int tid=threadIdx.x, wave=tid>>6, lane=tid&63;
  const int l15=lane&15, l4=lane>>4, l8r=lane>>3, l8c=lane&7;
  const int bid=blockIdx.x, xcd=bid&7, local=bid>>3;   // local 0..15
  const int mt=local>>2;                                // 0..3 (64-row batch tiles)
  const int jgroup=(local&3)*8+xcd;                     // 0..31
  const int dir=jgroup>>4, jt=jgroup&15;                // 16 j-tiles of 64
  const unsigned short* wih=dir?P.wihb:P.wihf;
  const unsigned short* whh=dir?P.whhb:P.whhf;
  const float* bih=dir?P.bihb:P.bihf;
  const float* bhh=dir?P.bhhb:P.bhhf;
  unsigned short* hbuf[2]={dir?P.hbb0:P.hfb0, dir?P.hbb1:P.hfb1};
  __shared__ unsigned short As[64*64];
  __shared__ unsigned short Bs[3*64*64];
  const int wm=(wave&1)*32, wn=(wave>>1)*32;
  float bR[2],bZ[2],bN[2],hRb[2],hZb[2],hNb[2];
#pragma unroll
  for (int nf=0;nf<2;++nf){
    int j=jt*64+wn+nf*16+l15;
    bR[nf]=bih[j]; bZ[nf]=bih[H+j]; bN[nf]=bih[2*H+j];
    hRb[nf]=bhh[j]; hZb[nf]=bhh[H+j]; hNb[nf]=bhh[2*H+j];
  }
  float hreg[2][2][4]={};
  unsigned tgt=0;

  for (int s=0;s<S;++s){
    const unsigned short* hsrc=hbuf[s&1];
    const int xs=dir?(S-1-s):s;
    const unsigned short* xsrc=P.xtb+(size_t)xs*B*V;
    f32x4 aR[2][2]={},aZ[2][2]={},aNH[2][2]={},aNX[2][2]={};
    // ---- hidden-path K phase (16 kt over H) ----
    for (int kt=0;kt<16;++kt){
      __syncthreads();
#pragma unroll
      for (int i=0;i<2;++i){             // A: 8 segs
        int seg=wave+i*4, row=seg*8+l8r, c=l8c^(row&7);
        stage16(hsrc+(size_t)(mt*64+row)*H+kt*64+c*8, &As[seg*8*64]);
      }
#pragma unroll
      for (int i=0;i<6;++i){             // B: 24 segs (3 gates x 64 rows)
        int seg=wave+i*4, row=seg*8+l8r, r=row&63, c=l8c^(r&7);
        int wrow=(row>>6)*H+jt*64+r;
        stage16(whh+(size_t)wrow*H+kt*64+c*8, &Bs[seg*8*64]);
      }
      __syncthreads();
#pragma unroll
      for (int kf=0;kf<2;++kf){
        int ch=kf*4+l4;
        bf16x8 a[2];
#pragma unroll
        for (int mi=0;mi<2;++mi){int ar=wm+mi*16+l15; a[mi]=*(const bf16x8*)&As[ar*64+((ch^(ar&7))<<3)];}
#pragma unroll
        for (int nf=0;nf<2;++nf){
          int br=wn+nf*16+l15, off=(ch^(br&7))<<3;
          bf16x8 b0=*(const bf16x8*)&Bs[br*64+off];
          bf16x8 b1=*(const bf16x8*)&Bs[(64+br)*64+off];
          bf16x8 b2=*(const bf16x8*)&Bs[(128+br)*64+off];
#pragma unroll
          for (int mi=0;mi<2;++mi){
            aR[mi][nf]=MFMA(a[mi],b0,aR[mi][nf]);
            aZ[mi][nf]=MFMA(a[mi],b1,aZ[mi][nf]);
            aNH[mi][nf]=MFMA(a[mi],b2,aNH[mi][nf]);
          }
        }
      }
    }
    // ---- input-path K phase (2 kt over V) ----
    for (int kt=0;kt<2;++kt){
      __syncthreads();
#pragma unroll
      for (int i=0;i<2;++i){
        int seg=wave+i*4, row=seg*8+l8r, c=l8c^(row&7);
        stage16(xsrc+(size_t)(mt*64+row)*V+kt*64+c*8, &As[seg*8*64]);
      }
#pragma unroll
      for (int i=0;i<6;++i){
        int seg=wave+i*4, row=seg*8+l8r, r=row&63, c=l8c^(r&7);
        int wrow=(row>>6)*H+jt*64+r;
        stage16(wih+(size_t)wrow*V+kt*64+c*8, &Bs[seg*8*64]);
      }
      __syncthreads();
#pragma unroll
      for (int kf=0;kf<2;++kf){
        int ch=kf*4+l4;
        bf16x8 a[2];
#pragma unroll
        for (int mi=0;mi<2;++mi){int ar=wm+mi*16+l15; a[mi]=*(const bf16x8*)&As[ar*64+((ch^(ar&7))<<3)];}
#pragma unroll
        for (int nf=0;nf<2;++nf){
          int br=wn+nf*16+l15, off=(ch^(br&7))<<3;
          bf16x8 b0=*(const bf16x8*)&Bs[br*64+off];
          bf16x8 b1=*(const bf16x8*)&Bs[(64+br)*64+off];
          bf16x8 b2=*(const bf16x8*)&Bs[(128+br)*64+off];
#pragma unroll
          for (int mi=0;mi<2;++mi){
            aR[mi][nf]=MFMA(a[mi],b0,aR[mi][nf]);
            aZ[mi][nf]=MFMA(a[mi],b1,aZ[mi][nf]);
            aNX[mi][nf]=MFMA(a[mi],b2,aNX[mi][nf]);
          }
        }
      }
    }
    // ---- fused GRU combine (h stays in registers) ----
    unsigned short* hdst=hbuf[(s+1)&1];
#pragma unroll
    for (int mi=0;mi<2;++mi)
#pragma unroll
      for (int nf=0;nf<2;++nf){
        int j=jt*64+wn+nf*16+l15;
#pragma unroll
        for (int r4=0;r4<4;++r4){
          int m=mt*64+wm+mi*16+l4*4+r4;
          float rg=sigm(aR[mi][nf][r4]+bR[nf]+hRb[nf]);
          float zg=sigm(aZ[mi][nf][r4]+bZ[nf]+hZb[nf]);
          float nn=tanhf(aNX[mi][nf][r4]+bN[nf]+rg*(aNH[mi][nf][r4]+hNb[nf]));
          float hnew=(1.f-zg)*nn+zg*hreg[mi][nf][r4];
          hreg[mi][nf][r4]=hnew;
          hdst[(size_t)m*H+j]=f2bf(hnew);
        }
      }
    gbar(P.bar, gridDim.x, tgt);
  }
  float* hout=dir?P.hb:P.hf;
#pragma unroll
  for (int mi=0;mi<2;++mi)
#pragma unroll
    for (int nf=0;nf<2;++nf){
      int j=jt*64+wn+nf*16+l15;
#pragma unroll
      for (int r4=0;r4<4;++r4){
        int m=mt*64+wm+mi*16+l4*4+r4;
        hout[(size_t)m*H+j]=hreg[mi][nf][r4];
      }
    }
}

// ---------------- persistent decoder ----------------
struct DecP {
  unsigned short *h1b0,*h1b1,*h2b0,*h2b1;
  const unsigned short *w1hh,*w2ih,*w2hh,*wout;
  const float *bhh1,*bih2,*bhh2,*bout;
  const float *zpart,*WT,*h1f;
  float *logits,*lsbuf,*recon;
  int* idxb;
  unsigned* bar;
};

__global__ __launch_bounds__(256,1) void k_dec(DecP P){
  union SH {
    struct { unsigned short A1[32*64]; unsigned short A2[32*64]; unsigned short Bt[6*64*64]; } g;
    struct { float ls[VC]; float rv[256]; int ri[256]; } sm;
  };
  __shared__ SH u;
  const int tid=threadIdx.x, wave=tid>>6, lane=tid&63;
  const int l15=lane&15, l4=lane>>4, l8r=lane>>3, l8c=lane&7;
  const int bid=blockIdx.x, xcd=bid&7, local=bid>>3;    // local 0..31
  const bool act12=(local<16);
  const int jt=(local&1)*8+xcd;                          // 0..15
  const int mt=(local>>1)&7;                             // 0..7 (32-row tiles)
  const int jt3=(local&3)*8+xcd;                         // 0..31
  const int mt3=local>>2;                                // 0..7
  const int wm=(wave&1)*16, wn=(wave>>1)*32;
  unsigned short* h1b[2]={P.h1b0,P.h1b1};
  unsigned short* h2b[2]={P.h2b0,P.h2b1};

  float h1reg[2][4]={}, h2reg[2][4]={};
  float zpR[2][4],zpZ[2][4],zpN[2][4];
  float b1R[2],b1Z[2],b1N[2];
  float c2R[2],c2Z[2],bi2N[2],bh2N[2];
  float bo3[2];
  if (act12){
#pragma unroll
    for (int nf=0;nf<2;++nf){
      int j=jt*64+wn+nf*16+l15;
      b1R[nf]=P.bhh1[j]; b1Z[nf]=P.bhh1[H+j]; b1N[nf]=P.bhh1[2*H+j];
      c2R[nf]=P.bih2[j]+P.bhh2[j]; c2Z[nf]=P.bih2[H+j]+P.bhh2[H+j];
      bi2N[nf]=P.bih2[2*H+j]; bh2N[nf]=P.bhh2[2*H+j];
#pragma unroll
      for (int r4=0;r4<4;++r4){
        int m=mt*32+wm+l4*4+r4;
        h1reg[nf][r4]=P.h1f[(size_t)m*H+j];
        zpR[nf][r4]=P.zpart[(size_t)m*G3+j];
        zpZ[nf][r4]=P.zpart[(size_t)m*G3+H+j];
        zpN[nf][r4]=P.zpart[(size_t)m*G3+2*H+j];
      }
    }
  }
#pragma unroll
  for (int nf=0;nf<2;++nf) bo3[nf]=P.bout[jt3*64+wn+nf*16+l15];

  unsigned tgt=0;
  for (int t=0;t<NSTEP;++t){
    const int cur=t&1, nxt=cur^1;
    // ---- stage1: gh1 GEMM + fused combine1 ----
    if (act12){
      const unsigned short* h1src=h1b[cur];
      f32x4 aR[2]={},aZ[2]={},aN[2]={};
      for (int kt=0;kt<16;++kt){
        __syncthreads();
        { int row=wave*8+l8r, c=l8c^(row&7);
          stage16(h1src+(size_t)(mt*32+row)*H+kt*64+c*8, &u.g.A1[wave*8*64]); }
#pragma unroll
        for (int i=0;i<6;++i){
          int seg=wave+i*4, row=seg*8+l8r, r=row&63, c=l8c^(r&7);
          int wrow=(row>>6)*H+jt*64+r;
          stage16(P.w1hh+(size_t)wrow*H+kt*64+c*8, &u.g.Bt[seg*8*64]);
        }
        __syncthreads();
#pragma unroll
        for (int kf=0;kf<2;++kf){
          int ch=kf*4+l4, ar=wm+l15;
          bf16x8 a=*(const bf16x8*)&u.g.A1[ar*64+((ch^(ar&7))<<3)];
#pragma unroll
          for (int nf=0;nf<2;++nf){
            int br=wn+nf*16+l15, off=(ch^(br&7))<<3;
            bf16x8 b0=*(const bf16x8*)&u.g.Bt[br*64+off];
            bf16x8 b1=*(const bf16x8*)&u.g.Bt[(64+br)*64+off];
            bf16x8 b2=*(const bf16x8*)&u.g.Bt[(128+br)*64+off];
            aR[nf]=MFMA(a,b0,aR[nf]); aZ[nf]=MFMA(a,b1,aZ[nf]); aN[nf]=MFMA(a,b2,aN[nf]);
          }
        }
      }
      int idxm[4];
#pragma unroll
      for (int r4=0;r4<4;++r4) idxm[r4]=P.idxb[mt*32+wm+l4*4+r4];
      unsigned short* h1dst=h1b[nxt];
#pragma unroll
      for (int nf=0;nf<2;++nf){
        int j=jt*64+wn+nf*16+l15;
#pragma unroll
        for (int r4=0;r4<4;++r4){
          const float* wt=P.WT+(size_t)idxm[r4]*G3;
          float rg=sigm(zpR[nf][r4]+wt[j]+aR[nf][r4]+b1R[nf]);
          float zg=sigm(zpZ[nf][r4]+wt[H+j]+aZ[nf][r4]+b1Z[nf]);
          float nn=tanhf(zpN[nf][r4]+wt[2*H+j]+rg*(aN[nf][r4]+b1N[nf]));
          float hnew=(1.f-zg)*nn+zg*h1reg[nf][r4];
          h1reg[nf][r4]=hnew;
          int m=mt*32+wm+l4*4+r4;
          h1dst[(size_t)m*H+j]=f2bf(hnew);
        }
      }
    }
    gbar(P.bar,256,tgt);   // A: h1 new visible
    // ---- stage2: gi2+gh2 GEMM + fused combine2 ----
    if (act12){
      const unsigned short* a1src=h1b[nxt];
      const unsigned short* a2src=(t==0)?h1b[nxt]:h2b[cur];
      f32x4 aR[2]={},aZ[2]={},aNI[2]={},aNH[2]={};
      for (int kt=0;kt<16;++kt){
        __syncthreads();
        { int row=wave*8+l8r, c=l8c^(row&7);
          stage16(a1src+(size_t)(mt*32+row)*H+kt*64+c*8, &u.g.A1[wave*8*64]);
          stage16(a2src+(size_t)(mt*32+row)*H+kt*64+c*8, &u.g.A2[wave*8*64]); }
#pragma unroll
        for (int i=0;i<12;++i){
          int seg=wave+i*4, row=seg*8+l8r, g6=row>>6, r=row&63, c=l8c^(r&7);
          const unsigned short* wsrc=(g6<3)?P.w2ih:P.w2hh;
          int wrow=(g6%3)*H+jt*64+r;
          stage16(wsrc+(size_t)wrow*H+kt*64+c*8, &u.g.Bt[seg*8*64]);
        }
        __syncthreads();
#pragma unroll
        for (int kf=0;kf<2;++kf){
          int ch=kf*4+l4, ar=wm+l15, aoff=(ch^(ar&7))<<3;
          bf16x8 a1=*(const bf16x8*)&u.g.A1[ar*64+aoff];
          bf16x8 a2=*(const bf16x8*)&u.g.A2[ar*64+aoff];
#pragma unroll
          for (int nf=0;nf<2;++nf){
            int br=wn+nf*16+l15, off=(ch^(br&7))<<3;
            bf16x8 bri=*(const bf16x8*)&u.g.Bt[br*64+off];
            bf16x8 bzi=*(const bf16x8*)&u.g.Bt[(64+br)*64+off];
            bf16x8 bni=*(const bf16x8*)&u.g.Bt[(128+br)*64+off];
            bf16x8 brh=*(const bf16x8*)&u.g.Bt[(192+br)*64+off];
            bf16x8 bzh=*(const bf16x8*)&u.g.Bt[(256+br)*64+off];
            bf16x8 bnh=*(const bf16x8*)&u.g.Bt[(320+br)*64+off];
            aR[nf]=MFMA(a1,bri,aR[nf]); aR[nf]=MFMA(a2,brh,aR[nf]);
            aZ[nf]=MFMA(a1,bzi,aZ[nf]); aZ[nf]=MFMA(a2,bzh,aZ[nf]);
            aNI[nf]=MFMA(a1,bni,aNI[nf]); aNH[nf]=MFMA(a2,bnh,aNH[nf]);
          }
        }
      }
      unsigned short* h2dst=h2b[nxt];
#pragma unroll
      for (int nf=0;nf<2;++nf){
        int j=jt*64+wn+nf*16+l15;
#pragma unroll
        for (int r4=0;r4<4;++r4){
          float rg=sigm(aR[nf][r4]+c2R[nf]);
          float zg=sigm(aZ[nf][r4]+c2Z[nf]);
          float nn=tanhf(aNI[nf][r4]+bi2N[nf]+rg*(aNH[nf][r4]+bh2N[nf]));
          float hp=(t==0)?h1reg[nf][r4]:h2reg[nf][r4];
          float hnew=(1.f-zg)*nn+zg*hp;
          h2reg[nf][r4]=hnew;
          int m=mt*32+wm+l4*4+r4;
          h2dst[(size_t)m*H+j]=f2bf(hnew);
        }
      }
    }
    gbar(P.bar,256,tgt);   // B: h2 new visible
    // ---- stage3: logits GEMM ----
    {
      const unsigned short* asrc=h2b[nxt];
      f32x4 acc[2]={};
      for (int kt=0;kt<16;++kt){
        __syncthreads();
        { int row=wave*8+l8r, c=l8c^(row&7);
          stage16(asrc+(size_t)(mt3*32+row)*H+kt*64+c*8, &u.g.A1[wave*8*64]); }
#pragma unroll
        for (int i=0;i<2;++i){
          int seg=wave+i*4, row=seg*8+l8r, c=l8c^(row&7);
          int wrow=jt3*64+row;
          stage16(P.wout+(size_t)wrow*H+kt*64+c*8, &u.g.Bt[seg*8*64]);
        }
        __syncthreads();
#pragma unroll
        for (int kf=0;kf<2;++kf){
          int ch=kf*4+l4, ar=wm+l15;
          bf16x8 a=*(const bf16x8*)&u.g.A1[ar*64+((ch^(ar&7))<<3)];
#pragma unroll
          for (int nf=0;nf<2;++nf){
            int br=wn+nf*16+l15, off=(ch^(br&7))<<3;
            bf16x8 b0=*(const bf16x8*)&u.g.Bt[br*64+off];
            acc[nf]=MFMA(a,b0,acc[nf]);
          }
        }
      }
#pragma unroll
      for (int nf=0;nf<2;++nf){
        int n=jt3*64+wn+nf*16+l15;
#pragma unroll
        for (int r4=0;r4<4;++r4){
          int m=mt3*32+wm+l4*4+r4;
          P.logits[(size_t)m*VC+n]=acc[nf][r4]+bo3[nf];
        }
      }
    }
    gbar(P.bar,256,tgt);   // C: logits visible
    // ---- stage4: log-softmax + argmax (block bid = row bid) ----
    {
      const int b=bid;
#pragma unroll
      for (int i=0;i<VC/256;++i){int n=tid+i*256; u.sm.ls[n]=P.logits[(size_t)b*VC+n];}
      __syncthreads();
      if (tid<V){
        float mx=-1e30f;
        for (int c=0;c<C;++c) mx=fmaxf(mx,u.sm.ls[c*V+tid]);
        float sum=0.f;
        for (int c=0;c<C;++c) sum+=expf(u.sm.ls[c*V+tid]-mx);
        float lse=mx+logf(sum);
        for (int c=0;c<C;++c) u.sm.ls[c*V+tid]-=lse;
      }
      __syncthreads();
      float bv=-1e30f; int bi=0;
#pragma unroll
      for (int i=0;i<VC/256;++i){
        int n=i*256+tid; float v=u.sm.ls[n];
        if (v>bv){bv=v;bi=n;}
      }
      u.sm.rv[tid]=bv; u.sm.ri[tid]=bi;
      __syncthreads();
      for (int s2=128;s2>0;s2>>=1){
        if (tid<s2){
          float v2=u.sm.rv[tid+s2]; int i2=u.sm.ri[tid+s2];
          if (v2>u.sm.rv[tid]||(v2==u.sm.rv[tid]&&i2<u.sm.ri[tid])){u.sm.rv[tid]=v2;u.sm.ri[tid]=i2;}
        }
        __syncthreads();
      }
      if (tid==0) P.idxb[b]=u.sm.ri[0];
      float* dst=P.lsbuf+(size_t)(t&15)*B*VC+(size_t)b*VC;
#pragma unroll
      for (int i=0;i<VC/256;++i){int n=tid+i*256; dst[n]=u.sm.ls[n];}
    }
    gbar(P.bar,256,tgt);   // D: idxb + lsbuf visible
    // ---- flush staged log-softmax to recon (coalesced) ----
    if ((t&15)==15){
      int t0=t-15, base=bid*256+tid;
#pragma unroll
      for (int i=0;i<8;++i){
        int e=base+i*65536;
        float* dst=P.recon+(size_t)e*NSTEP+t0;
#pragma unroll
        for (int j2=0;j2<16;++j2) dst[j2]=P.lsbuf[(size_t)j2*B*VC+e];
      }
    }
  }
}

// ---------------- host orchestration ----------------
extern "C" void kernel_launch(void* const* d_in, const int* in_sizes, int n_in,
                              void* d_out, int out_size, void* d_ws, size_t ws_size,
                              hipStream_t stream) {
  const float* x        = (const float*)d_in[0];
  const float* noise    = (const float*)d_in[1];
  const float* gruf_Wih = (const float*)d_in[2];
  const float* gruf_Whh = (const float*)d_in[3];
  const float* gruf_bih = (const float*)d_in[4];
  const float* gruf_bhh = (const float*)d_in[5];
  const float* grub_Wih = (const float*)d_in[6];
  const float* grub_Whh = (const float*)d_in[7];
  const float* grub_bih = (const float*)d_in[8];
  const float* grub_bhh = (const float*)d_in[9];
  const float* Wmu      = (const float*)d_in[10];
  const float* bmu      = (const float*)d_in[11];
  const float* Wvar     = (const float*)d_in[12];
  const float* bvar     = (const float*)d_in[13];
  const float* Winit    = (const float*)d_in[14];
  const float* binit    = (const float*)d_in[15];
  const float* c1_Wih   = (const float*)d_in[16];
  const float* c1_Whh   = (const float*)d_in[17];
  const float* c1_bih   = (const float*)d_in[18];
  const float* c1_bhh   = (const float*)d_in[19];
  const float* c2_Wih   = (const float*)d_in[20];
  const float* c2_Whh   = (const float*)d_in[21];
  const float* c2_bih   = (const float*)d_in[22];
  const float* c2_bhh   = (const float*)d_in[23];
  const float* Wout     = (const float*)d_in[24];
  const float* bout     = (const float*)d_in[25];

  float* omu = (float*)d_out;
  float* ovar = omu + B*Z;
  float* oz = ovar + B*Z;
  float* orecon = oz + B*Z;

  char* p = (char*)d_ws;
  auto carve = [&](size_t bytes){ char* r = p; p += (bytes+255)&~(size_t)255; return r; };
  unsigned short* wihf_b  = (unsigned short*)carve((size_t)G3*V*2);
  unsigned short* whhf_b  = (unsigned short*)carve((size_t)G3*H*2);
  unsigned short* wihb_b  = (unsigned short*)carve((size_t)G3*V*2);
  unsigned short* whhb_b  = (unsigned short*)carve((size_t)G3*H*2);
  unsigned short* wc1hh_b = (unsigned short*)carve((size_t)G3*H*2);
  unsigned short* wc2ih_b = (unsigned short*)carve((size_t)G3*H*2);
  unsigned short* wc2hh_b = (unsigned short*)carve((size_t)G3*H*2);
  unsigned short* wout_b  = (unsigned short*)carve((size_t)VC*H*2);
  unsigned short* xtb     = (unsigned short*)carve((size_t)S*B*V*2);
  unsigned short* hfb0    = (unsigned short*)carve((size_t)B*H*2);
  unsigned short* hfb1    = (unsigned short*)carve((size_t)B*H*2);
  unsigned short* hbb0    = (unsigned short*)carve((size_t)B*H*2);
  unsigned short* hbb1    = (unsigned short*)carve((size_t)B*H*2);
  unsigned short* h1b0    = (unsigned short*)carve((size_t)B*H*2);
  unsigned short* h1b1    = (unsigned short*)carve((size_t)B*H*2);
  unsigned short* h2b0    = (unsigned short*)carve((size_t)B*H*2);
  unsigned short* h2b1    = (unsigned short*)carve((size_t)B*H*2);
  float* WT     = (float*)carve((size_t)VC*G3*4);
  float* zpart  = (float*)carve((size_t)B*G3*4);
  float* hf     = (float*)carve((size_t)B*H*4);
  float* hb     = (float*)carve((size_t)B*H*4);
  float* h1f    = (float*)carve((size_t)B*H*4);
  float* zws    = (float*)carve((size_t)B*Z*4);
  float* logits = (float*)carve((size_t)B*VC*4);
  float* lsbuf  = (float*)carve((size_t)16*B*VC*4);
  int* idxb     = (int*)carve((size_t)B*4);
  unsigned* bars= (unsigned*)carve(2*sizeof(unsigned));

  dim3 blk(256);
  auto cvt=[&](const float* s, unsigned short* d, int n){
    int nb=(n+255)/256; if (nb>2048) nb=2048;
    k_cvt<<<nb,blk,0,stream>>>(s,d,n);
  };
  cvt(gruf_Wih,wihf_b,G3*V);
  cvt(gruf_Whh,whhf_b,G3*H);
  cvt(grub_Wih,wihb_b,G3*V);
  cvt(grub_Whh,whhb_b,G3*H);
  cvt(c1_Whh,wc1hh_b,G3*H);
  cvt(c2_Wih,wc2ih_b,G3*H);
  cvt(c2_Whh,wc2hh_b,G3*H);
  cvt(Wout,wout_b,VC*H);
  k_xt<<<dim3(S/32,(B*V)/32),dim3(32,8),0,stream>>>(x,xtb);
  k_wt<<<dim3(VC/32,G3/32),dim3(32,8),0,stream>>>(c1_Wih,WT);
  hipMemsetAsync(hfb0,0,(size_t)B*H*2,stream);
  hipMemsetAsync(hbb0,0,(size_t)B*H*2,stream);
  hipMemsetAsync(bars,0,2*sizeof(unsigned),stream);

  EncP ep;
  ep.xtb=xtb; ep.wihf=wihf_b; ep.whhf=whhf_b; ep.wihb=wihb_b; ep.whhb=whhb_b;
  ep.bihf=gruf_bih; ep.bhhf=gruf_bhh; ep.bihb=grub_bih; ep.bhhb=grub_bhh;
  ep.hfb0=hfb0; ep.hfb1=hfb1; ep.hbb0=hbb0; ep.hbb1=hbb1;
  ep.hf=hf; ep.hb=hb; ep.bar=bars;
  k_enc<<<128,blk,0,stream>>>(ep);

  k_mu_var_z<<<B,blk,0,stream>>>(hf,hb,Wmu,bmu,Wvar,bvar,noise,omu,ovar,oz,zws);
  k_zpart<<<B*G3/256,blk,0,stream>>>(zws,c1_Wih,c1_bih,zpart);
  k_h1init<<<B*H/256,blk,0,stream>>>(zws,Winit,binit,h1f,h1b0,idxb);

  DecP dp;
  dp.h1b0=h1b0; dp.h1b1=h1b1; dp.h2b0=h2b0; dp.h2b1=h2b1;
  dp.w1hh=wc1hh_b; dp.w2ih=wc2ih_b; dp.w2hh=wc2hh_b; dp.wout=wout_b;
  dp.bhh1=c1_bhh; dp.bih2=c2_bih; dp.bhh2=c2_bhh; dp.bout=bout;
  dp.zpart=zpart; dp.WT=WT; dp.h1f=h1f;
  dp.logits=logits; dp.lsbuf=lsbuf; dp.recon=orecon;
  dp.idxb=idxb; dp.bar=bars+1;
  k_dec<<<256,blk,0,stream>>>(dp);
}

// Round 3
// 12425.867 us; speedup vs baseline: 2.0818x; 2.0818x over previous
//
#include <hip/hip_runtime.h>
#include <cstdint>
#include <cstddef>

typedef __attribute__((ext_vector_type(8))) short bf16x8;
typedef __attribute__((ext_vector_type(4))) float f32x4;
#define DEVI __device__ __forceinline__

constexpr int B = 256, S = 128, V = 128, C = 16, H = 1024, Z = 256, NSTEP = 128;
constexpr int VC = V * C, G3 = 3 * H;
constexpr size_t BVC = (size_t)B * VC;

typedef __attribute__((address_space(1))) const unsigned short* gas_p;
typedef __attribute__((address_space(3))) unsigned short* las_p;

DEVI unsigned short f2bf(float f){unsigned u=__float_as_uint(f);u+=0x7fffu+((u>>16)&1u);return (unsigned short)(u>>16);}
DEVI float sigm(float x){return 1.f/(1.f+expf(-x));}
DEVI f32x4 MFMA(bf16x8 a,bf16x8 b,f32x4 c){return __builtin_amdgcn_mfma_f32_16x16x32_bf16(a,b,c,0,0,0);}
DEVI void stage16(const unsigned short* g, unsigned short* l){__builtin_amdgcn_global_load_lds((gas_p)g,(las_p)l,16,0,0);}

// ---- coherent (cross-XCD safe, L2-bypassing) access helpers ----
DEVI unsigned long long ldc8(const void* p){return __hip_atomic_load((unsigned long long*)p,__ATOMIC_RELAXED,__HIP_MEMORY_SCOPE_AGENT);}
DEVI void stc8(void* p, unsigned long long v){__hip_atomic_store((unsigned long long*)p,v,__ATOMIC_RELAXED,__HIP_MEMORY_SCOPE_AGENT);}
DEVI unsigned ldc4(const void* p){return __hip_atomic_load((unsigned*)p,__ATOMIC_RELAXED,__HIP_MEMORY_SCOPE_AGENT);}
DEVI void stc4(void* p, unsigned v){__hip_atomic_store((unsigned*)p,v,__ATOMIC_RELAXED,__HIP_MEMORY_SCOPE_AGENT);}
DEVI bf16x8 ldfragc(const unsigned short* p){
  union { bf16x8 v; unsigned long long q[2]; } u;
  u.q[0]=ldc8(p); u.q[1]=ldc8(p+4); return u.v;
}
DEVI unsigned long long pack4(float a,float b,float c,float d){
  return (unsigned long long)f2bf(a)|((unsigned long long)f2bf(b)<<16)|((unsigned long long)f2bf(c)<<32)|((unsigned long long)f2bf(d)<<48);
}
DEVI unsigned long long packf2(float a,float b){
  return (unsigned long long)__float_as_uint(a)|((unsigned long long)__float_as_uint(b)<<32);
}

// ---- fence-free two-level grid barrier (256 blocks = 32 groups x 8) ----
// layout in u32: grp[g] at bb[g*32]; root at bb[1024]; rel[g] at bb[1056+g*32]
DEVI void gbar(unsigned* bb, int bid, unsigned p){
  asm volatile("s_waitcnt vmcnt(0) lgkmcnt(0)" ::: "memory"); // all waves drain own VMEM (coherent stores done)
  __syncthreads();
  if (threadIdx.x==0){
    int g=bid>>3;
    unsigned* grp=&bb[g*32];
    unsigned* root=&bb[1024];
    unsigned* rel=&bb[1056+g*32];
    __hip_atomic_fetch_add(grp,1u,__ATOMIC_RELAXED,__HIP_MEMORY_SCOPE_AGENT);
    if ((bid&7)==0){
      while (__hip_atomic_load(grp,__ATOMIC_RELAXED,__HIP_MEMORY_SCOPE_AGENT) < 8u*p) __builtin_amdgcn_s_sleep(1);
      __hip_atomic_fetch_add(root,1u,__ATOMIC_RELAXED,__HIP_MEMORY_SCOPE_AGENT);
      while (__hip_atomic_load(root,__ATOMIC_RELAXED,__HIP_MEMORY_SCOPE_AGENT) < 32u*p) __builtin_amdgcn_s_sleep(1);
      __hip_atomic_store(rel,p,__ATOMIC_RELAXED,__HIP_MEMORY_SCOPE_AGENT);
    } else {
      while (__hip_atomic_load(rel,__ATOMIC_RELAXED,__HIP_MEMORY_SCOPE_AGENT) < p) __builtin_amdgcn_s_sleep(1);
    }
  }
  __syncthreads();
}

// ---------------- prep kernels ----------------
__global__ void k_cvt(const float* __restrict__ src, unsigned short* __restrict__ dst, int n){
  for (int i=blockIdx.x*256+threadIdx.x;i<n;i+=gridDim.x*256) dst[i]=f2bf(src[i]);
}

__global__ void k_xt(const float* __restrict__ x, unsigned short* __restrict__ xtb){
  __shared__ float tile[32][33];
  int sb=blockIdx.x*32, rb=blockIdx.y*32, tx=threadIdx.x, ty=threadIdx.y;
  for (int i=ty;i<32;i+=8) tile[i][tx]=x[(size_t)(rb+i)*S+sb+tx];
  __syncthreads();
  for (int i=ty;i<32;i+=8) xtb[(size_t)(sb+i)*(B*V)+rb+tx]=f2bf(tile[tx][i]);
}

__global__ void k_wt(const float* __restrict__ w, float* __restrict__ wt){
  __shared__ float tile[32][33];
  int vb=blockIdx.x*32, nb=blockIdx.y*32, tx=threadIdx.x, ty=threadIdx.y;
  for (int i=ty;i<32;i+=8) tile[i][tx]=w[(size_t)(nb+i)*(VC+Z)+vb+tx];
  __syncthreads();
  for (int i=ty;i<32;i+=8) wt[(size_t)(vb+i)*G3+nb+tx]=tile[tx][i];
}

__global__ __launch_bounds__(256) void k_mu_var_z(const float* __restrict__ hf,const float* __restrict__ hb,
    const float* __restrict__ Wmu,const float* __restrict__ bmu,
    const float* __restrict__ Wvar,const float* __restrict__ bvar,
    const float* __restrict__ noise,
    float* __restrict__ omu,float* __restrict__ ovar,float* __restrict__ oz,float* __restrict__ zws){
  __shared__ float e[2*H];
  int b=blockIdx.x, t=threadIdx.x;
  for (int i=0;i<2*H/256;++i){int k=t+i*256; e[k]=(k<H)?hf[b*H+k]:hb[b*H+k-H];}
  __syncthreads();
  const float* wm=Wmu+(size_t)t*2*H; const float* wv=Wvar+(size_t)t*2*H;
  float am=bmu[t], av=bvar[t];
  for (int k=0;k<2*H;++k){am+=e[k]*wm[k];av+=e[k]*wv[k];}
  float vv=expf(av), zz=am+vv*noise[b*Z+t];
  omu[b*Z+t]=am; ovar[b*Z+t]=vv; oz[b*Z+t]=zz; zws[b*Z+t]=zz;
}

__global__ void k_zpart(const float* __restrict__ z,const float* __restrict__ c1Wih,
                        const float* __restrict__ bih,float* __restrict__ zpart){
  int idx=blockIdx.x*256+threadIdx.x;
  int b=idx/G3, n=idx%G3;
  const float* w=c1Wih+(size_t)n*(VC+Z)+VC;
  const float* zr=z+b*Z;
  float a=bih[n];
  for (int k=0;k<Z;++k) a+=zr[k]*w[k];
  zpart[idx]=a;
}

__global__ void k_h1init(const float* __restrict__ z,const float* __restrict__ Winit,
                         const float* __restrict__ binit,
                         float* __restrict__ h1f,unsigned short* __restrict__ h1b,int* __restrict__ idxb){
  int idx=blockIdx.x*256+threadIdx.x;
  int b=idx>>10, jj=idx&(H-1);
  const float* w=Winit+(size_t)jj*Z;
  const float* zr=z+b*Z;
  float a=binit[jj];
  for (int k=0;k<Z;++k) a+=zr[k]*w[k];
  float t=tanhf(a);
  h1f[idx]=t; h1b[idx]=f2bf(t);
  if (idx<B) idxb[idx]=VC-1;
}

// ---------------- persistent encoder (256 blocks) ----------------
struct EncP {
  const unsigned short *xtb,*wihf,*whhf,*wihb,*whhb;
  const float *bihf,*bhhf,*bihb,*bhhb;
  unsigned short *hf0,*hf1,*hb0,*hb1;
  float *hf,*hb;
  unsigned* bar;
};

__global__ __launch_bounds__(256,1) void k_enc(EncP P){
  __shared__ unsigned short st[4*3*32*64];
  const int tid=threadIdx.x, wave=tid>>6, lane=tid&63;
  const int l15=lane&15, l4=lane>>4, l8r=lane>>3, l8c=lane&7;
  const int bid=blockIdx.x, xcd=bid&7, q=bid>>3;
  const int dir=q>>4, q2=q&15, jt=(q2&1)*8+xcd, mt=q2>>1;
  const int wm=(wave&1)*16, wn=(wave>>1)*32;
  const unsigned short* wih=dir?P.wihb:P.wihf;
  const unsigned short* whh=dir?P.whhb:P.whhf;
  const float* bih=dir?P.bihb:P.bihf;
  const float* bhh=dir?P.bhhb:P.bhhf;
  unsigned short* hbuf[2]={dir?P.hb0:P.hf0, dir?P.hb1:P.hf1};
  unsigned short* lw=&st[wave*3*32*64];
  const int mrow=mt*32+wm+l15;

  f32x4 biR[2],biZ[2],biN[2],bhR[2],bhZ[2],bhN[2];
#pragma unroll
  for (int nj=0;nj<2;++nj){
    int j0=jt*64+wn+nj*16+(l4<<2);
    biR[nj]=*(const f32x4*)&bih[j0]; biZ[nj]=*(const f32x4*)&bih[H+j0]; biN[nj]=*(const f32x4*)&bih[2*H+j0];
    bhR[nj]=*(const f32x4*)&bhh[j0]; bhZ[nj]=*(const f32x4*)&bhh[H+j0]; bhN[nj]=*(const f32x4*)&bhh[2*H+j0];
  }
  float hreg[2][4]={};

  for (int s=0;s<S;++s){
    const unsigned short* hsrc=hbuf[s&1];
    unsigned short* hdst=hbuf[(s+1)&1];
    const int xs=dir?(S-1-s):s;
    f32x4 aR[2]={},aZ[2]={},aNH[2]={},aNX[2]={};
    bf16x8 hc0=ldfragc(hsrc+(size_t)mrow*H+(l4<<3));
    bf16x8 hc1=ldfragc(hsrc+(size_t)mrow*H+((4+l4)<<3));
    // hidden path: K over H, B = whh (per-wave independent, swizzled stage)
    for (int kt=0;kt<16;++kt){
      const int kb=kt<<6;
#pragma unroll
      for (int g=0;g<3;++g)
#pragma unroll
        for (int i=0;i<4;++i)
          stage16(whh+(size_t)(g*H+jt*64+wn+i*8+l8r)*H+kb+((l8c^l8r)<<3), lw+(g*32+i*8)*64);
      asm volatile("" ::: "memory");
      const int kbn=(kt<15)?kb+64:kb;
      bf16x8 hn0=ldfragc(hsrc+(size_t)mrow*H+kbn+(l4<<3));
      bf16x8 hn1=ldfragc(hsrc+(size_t)mrow*H+kbn+((4+l4)<<3));
      asm volatile("s_waitcnt vmcnt(4)" ::: "memory");
#pragma unroll
      for (int kf=0;kf<2;++kf){
        const int ch=(kf<<2)+l4, sw=((ch^(l15&7))<<3);
        bf16x8 hfr=kf?hc1:hc0;
#pragma unroll
        for (int nj=0;nj<2;++nj){
          int ro=(nj*16+l15)*64+sw;
          bf16x8 w0=*(const bf16x8*)&lw[ro];
          bf16x8 w1=*(const bf16x8*)&lw[2048+ro];
          bf16x8 w2=*(const bf16x8*)&lw[4096+ro];
          aR[nj]=MFMA(w0,hfr,aR[nj]); aZ[nj]=MFMA(w1,hfr,aZ[nj]); aNH[nj]=MFMA(w2,hfr,aNH[nj]);
        }
      }
      asm volatile("s_waitcnt lgkmcnt(0)" ::: "memory");
      hc0=hn0; hc1=hn1;
    }
    // input path: K over V, B = wih
#pragma unroll
    for (int kt=0;kt<2;++kt){
      const int kb=kt<<6;
#pragma unroll
      for (int g=0;g<3;++g)
#pragma unroll
        for (int i=0;i<4;++i)
          stage16(wih+(size_t)(g*H+jt*64+wn+i*8+l8r)*V+kb+((l8c^l8r)<<3), lw+(g*32+i*8)*64);
      asm volatile("s_waitcnt vmcnt(0)" ::: "memory");
#pragma unroll
      for (int kf=0;kf<2;++kf){
        const int ch=(kf<<2)+l4, sw=((ch^(l15&7))<<3);
        bf16x8 xf=*(const bf16x8*)&P.xtb[(size_t)xs*(B*V)+(size_t)mrow*V+kb+(ch<<3)];
#pragma unroll
        for (int nj=0;nj<2;++nj){
          int ro=(nj*16+l15)*64+sw;
          bf16x8 w0=*(const bf16x8*)&lw[ro];
          bf16x8 w1=*(const bf16x8*)&lw[2048+ro];
          bf16x8 w2=*(const bf16x8*)&lw[4096+ro];
          aR[nj]=MFMA(w0,xf,aR[nj]); aZ[nj]=MFMA(w1,xf,aZ[nj]); aNX[nj]=MFMA(w2,xf,aNX[nj]);
        }
      }
      asm volatile("s_waitcnt lgkmcnt(0)" ::: "memory");
    }
    // fused GRU combine; h stays in registers, bf16 copy published coherently
#pragma unroll
    for (int nj=0;nj<2;++nj){
      int j0=jt*64+wn+nj*16+(l4<<2);
      float hv[4];
#pragma unroll
      for (int r=0;r<4;++r){
        float rg=sigm(aR[nj][r]+biR[nj][r]+bhR[nj][r]);
        float zg=sigm(aZ[nj][r]+biZ[nj][r]+bhZ[nj][r]);
        float nn=tanhf(aNX[nj][r]+biN[nj][r]+rg*(aNH[nj][r]+bhN[nj][r]));
        float hnew=(1.f-zg)*nn+zg*hreg[nj][r];
        hreg[nj][r]=hnew; hv[r]=hnew;
      }
      stc8(hdst+(size_t)mrow*H+j0, pack4(hv[0],hv[1],hv[2],hv[3]));
    }
    gbar(P.bar,bid,(unsigned)(s+1));
  }
  float* hout=dir?P.hb:P.hf;
#pragma unroll
  for (int nj=0;nj<2;++nj){
    int j0=jt*64+wn+nj*16+(l4<<2);
    f32x4 v; v[0]=hreg[nj][0];v[1]=hreg[nj][1];v[2]=hreg[nj][2];v[3]=hreg[nj][3];
    *(f32x4*)&hout[(size_t)mrow*H+j0]=v;
  }
}

// ---------------- persistent decoder (256 blocks) ----------------
struct DecP {
  unsigned short *h1b0,*h1b1,*h2b0,*h2b1;
  const unsigned short *w1hh,*w2ih,*w2hh,*wout;
  const float *bhh1,*bih2,*bhh2,*bout;
  const float *zpart,*WT,*h1f;
  float *logits,*lsbuf,*recon;
  int* idxb;
  unsigned* bar;
};

__global__ __launch_bounds__(256,1) void k_dec(DecP P){
  union SH {
    unsigned short st[4*6*16*64];
    struct { float ls[VC]; float rv[256]; int ri[256]; } sm;
  };
  __shared__ SH u;
  const int tid=threadIdx.x, wave=tid>>6, lane=tid&63;
  const int l15=lane&15, l4=lane>>4, l8r=lane>>3, l8c=lane&7;
  const int bid=blockIdx.x, xcd=bid&7, q=bid>>3;
  const int jt=(q&3)*8+xcd, mt=q>>2;             // stages 1-2: 32 j, 32 m
  const int nt=jt, mt3=mt;                        // stage 3: 64 n, 32 m
  const int wm=(wave&1)*16, wn=(wave>>1)*16;      // stages 1-2
  const int wn3=(wave>>1)*32;                     // stage 3
  unsigned short* lw=&u.st[wave*6*16*64];
  unsigned short* h1b[2]={P.h1b0,P.h1b1};
  unsigned short* h2b[2]={P.h2b0,P.h2b1};
  const int mrow=mt*32+wm+l15;
  const int j0=jt*32+wn+(l4<<2);

  // hoisted step-invariants
  f32x4 zR4=*(const f32x4*)&P.zpart[(size_t)mrow*G3+j0];
  f32x4 zZ4=*(const f32x4*)&P.zpart[(size_t)mrow*G3+H+j0];
  f32x4 zN4=*(const f32x4*)&P.zpart[(size_t)mrow*G3+2*H+j0];
  f32x4 b1R=*(const f32x4*)&P.bhh1[j0], b1Z=*(const f32x4*)&P.bhh1[H+j0], b1N=*(const f32x4*)&P.bhh1[2*H+j0];
  f32x4 c2Rv, c2Zv, biN2, bhN2;
  { f32x4 a=*(const f32x4*)&P.bih2[j0],   b2=*(const f32x4*)&P.bhh2[j0];   c2Rv=a+b2; }
  { f32x4 a=*(const f32x4*)&P.bih2[H+j0], b2=*(const f32x4*)&P.bhh2[H+j0]; c2Zv=a+b2; }
  biN2=*(const f32x4*)&P.bih2[2*H+j0]; bhN2=*(const f32x4*)&P.bhh2[2*H+j0];
  f32x4 bo0=*(const f32x4*)&P.bout[nt*64+wn3+(l4<<2)];
  f32x4 bo1=*(const f32x4*)&P.bout[nt*64+wn3+16+(l4<<2)];
  f32x4 h1i=*(const f32x4*)&P.h1f[(size_t)mrow*H+j0];
  float h1reg[4]={h1i[0],h1i[1],h1i[2],h1i[3]};
  float h2reg[4]={};

  for (int t=0;t<NSTEP;++t){
    const int cur=t&1, nxt=cur^1;
    // ---- stage1: gh1 GEMM + fused combine1 ----
    {
      const unsigned short* h1src=h1b[cur];
      f32x4 aR={},aZ={},aN={};
      bf16x8 hc0=ldfragc(h1src+(size_t)mrow*H+(l4<<3));
      bf16x8 hc1=ldfragc(h1src+(size_t)mrow*H+((4+l4)<<3));
      for (int kt=0;kt<16;++kt){
        const int kb=kt<<6;
#pragma unroll
        for (int g=0;g<3;++g)
#pragma unroll
          for (int i=0;i<2;++i)
            stage16(P.w1hh+(size_t)(g*H+jt*32+wn+i*8+l8r)*H+kb+((l8c^l8r)<<3), lw+(g*16+i*8)*64);
        asm volatile("" ::: "memory");
        const int kbn=(kt<15)?kb+64:kb;
        bf16x8 hn0=ldfragc(h1src+(size_t)mrow*H+kbn+(l4<<3));
        bf16x8 hn1=ldfragc(h1src+(size_t)mrow*H+kbn+((4+l4)<<3));
        asm volatile("s_waitcnt vmcnt(4)" ::: "memory");
#pragma unroll
        for (int kf=0;kf<2;++kf){
          const int ch=(kf<<2)+l4, sw=((ch^(l15&7))<<3);
          int ro=l15*64+sw;
          bf16x8 w0=*(const bf16x8*)&lw[ro];
          bf16x8 w1=*(const bf16x8*)&lw[1024+ro];
          bf16x8 w2=*(const bf16x8*)&lw[2048+ro];
          bf16x8 hfr=kf?hc1:hc0;
          aR=MFMA(w0,hfr,aR); aZ=MFMA(w1,hfr,aZ); aN=MFMA(w2,hfr,aN);
        }
        asm volatile("s_waitcnt lgkmcnt(0)" ::: "memory");
        hc0=hn0; hc1=hn1;
      }
      int idxm=(int)ldc4(&P.idxb[mrow]);
      const float* wtr=P.WT+(size_t)idxm*G3;
      f32x4 wR=*(const f32x4*)&wtr[j0], wZ=*(const f32x4*)&wtr[H+j0], wN=*(const f32x4*)&wtr[2*H+j0];
      float hv[4];
#pragma unroll
      for (int r=0;r<4;++r){
        float rg=sigm(zR4[r]+wR[r]+aR[r]+b1R[r]);
        float zg=sigm(zZ4[r]+wZ[r]+aZ[r]+b1Z[r]);
        float nn=tanhf(zN4[r]+wN[r]+rg*(aN[r]+b1N[r]));
        float hnew=(1.f-zg)*nn+zg*h1reg[r];
        h1reg[r]=hnew; hv[r]=hnew;
      }
      stc8(h1b[nxt]+(size_t)mrow*H+j0, pack4(hv[0],hv[1],hv[2],hv[3]));
    }
    gbar(P.bar,bid,(unsigned)(4*t+1));
    // ---- stage2: gi2+gh2 GEMM + fused combine2 ----
    {
      const unsigned short* s1=h1b[nxt];
      const unsigned short* s2=(t==0)?h1b[nxt]:h2b[cur];
      f32x4 aR={},aZ={},aNI={},aNH={};
      bf16x8 a1c0=ldfragc(s1+(size_t)mrow*H+(l4<<3));
      bf16x8 a1c1=ldfragc(s1+(size_t)mrow*H+((4+l4)<<3));
      bf16x8 a2c0=ldfragc(s2+(size_t)mrow*H+(l4<<3));
      bf16x8 a2c1=ldfragc(s2+(size_t)mrow*H+((4+l4)<<3));
      for (int kt=0;kt<16;++kt){
        const int kb=kt<<6;
#pragma unroll
        for (int g=0;g<3;++g)
#pragma unroll
          for (int i=0;i<2;++i){
            stage16(P.w2ih+(size_t)(g*H+jt*32+wn+i*8+l8r)*H+kb+((l8c^l8r)<<3), lw+(g*16+i*8)*64);
            stage16(P.w2hh+(size_t)(g*H+jt*32+wn+i*8+l8r)*H+kb+((l8c^l8r)<<3), lw+((3+g)*16+i*8)*64);
          }
        asm volatile("" ::: "memory");
        const int kbn=(kt<15)?kb+64:kb;
        bf16x8 a1n0=ldfragc(s1+(size_t)mrow*H+kbn+(l4<<3));
        bf16x8 a1n1=ldfragc(s1+(size_t)mrow*H+kbn+((4+l4)<<3));
        bf16x8 a2n0=ldfragc(s2+(size_t)mrow*H+kbn+(l4<<3));
        bf16x8 a2n1=ldfragc(s2+(size_t)mrow*H+kbn+((4+l4)<<3));
        asm volatile("s_waitcnt vmcnt(8)" ::: "memory");
#pragma unroll
        for (int kf=0;kf<2;++kf){
          const int ch=(kf<<2)+l4, sw=((ch^(l15&7))<<3);
          int ro=l15*64+sw;
          bf16x8 wi0=*(const bf16x8*)&lw[ro];
          bf16x8 wi1=*(const bf16x8*)&lw[1024+ro];
          bf16x8 wi2=*(const bf16x8*)&lw[2048+ro];
          bf16x8 wh0=*(const bf16x8*)&lw[3072+ro];
          bf16x8 wh1=*(const bf16x8*)&lw[4096+ro];
          bf16x8 wh2=*(const bf16x8*)&lw[5120+ro];
          bf16x8 a1=kf?a1c1:a1c0, a2=kf?a2c1:a2c0;
          aR=MFMA(wi0,a1,aR); aR=MFMA(wh0,a2,aR);
          aZ=MFMA(wi1,a1,aZ); aZ=MFMA(wh1,a2,aZ);
          aNI=MFMA(wi2,a1,aNI); aNH=MFMA(wh2,a2,aNH);
        }
        asm volatile("s_waitcnt lgkmcnt(0)" ::: "memory");
        a1c0=a1n0;a1c1=a1n1;a2c0=a2n0;a2c1=a2n1;
      }
      float hv[4];
#pragma unroll
      for (int r=0;r<4;++r){
        float rg=sigm(aR[r]+c2Rv[r]);
        float zg=sigm(aZ[r]+c2Zv[r]);
        float nn=tanhf(aNI[r]+biN2[r]+rg*(aNH[r]+bhN2[r]));
        float hp=(t==0)?h1reg[r]:h2reg[r];
        float hnew=(1.f-zg)*nn+zg*hp;
        h2reg[r]=hnew; hv[r]=hnew;
      }
      stc8(h2b[nxt]+(size_t)mrow*H+j0, pack4(hv[0],hv[1],hv[2],hv[3]));
    }
    gbar(P.bar,bid,(unsigned)(4*t+2));
    // ---- stage3: logits GEMM (64 n per block) ----
    {
      const unsigned short* hs=h2b[nxt];
      const int m3row=mt3*32+wm+l15;
      f32x4 ac0={},ac1={};
      bf16x8 hc0=ldfragc(hs+(size_t)m3row*H+(l4<<3));
      bf16x8 hc1=ldfragc(hs+(size_t)m3row*H+((4+l4)<<3));
      for (int kt=0;kt<16;++kt){
        const int kb=kt<<6;
#pragma unroll
        for (int i=0;i<4;++i)
          stage16(P.wout+(size_t)(nt*64+wn3+i*8+l8r)*H+kb+((l8c^l8r)<<3), lw+i*8*64);
        asm volatile("" ::: "memory");
        const int kbn=(kt<15)?kb+64:kb;
        bf16x8 hn0=ldfragc(hs+(size_t)m3row*H+kbn+(l4<<3));
        bf16x8 hn1=ldfragc(hs+(size_t)m3row*H+kbn+((4+l4)<<3));
        asm volatile("s_waitcnt vmcnt(4)" ::: "memory");
#pragma unroll
        for (int kf=0;kf<2;++kf){
          const int ch=(kf<<2)+l4, sw=((ch^(l15&7))<<3);
          bf16x8 hfr=kf?hc1:hc0;
          bf16x8 w0=*(const bf16x8*)&lw[l15*64+sw];
          bf16x8 w1=*(const bf16x8*)&lw[(16+l15)*64+sw];
          ac0=MFMA(w0,hfr,ac0); ac1=MFMA(w1,hfr,ac1);
        }
        asm volatile("s_waitcnt lgkmcnt(0)" ::: "memory");
        hc0=hn0;hc1=hn1;
      }
      {
        int n0=nt*64+wn3+(l4<<2);
        stc8(&P.logits[(size_t)m3row*VC+n0],   packf2(ac0[0]+bo0[0],ac0[1]+bo0[1]));
        stc8(&P.logits[(size_t)m3row*VC+n0+2], packf2(ac0[2]+bo0[2],ac0[3]+bo0[3]));
        int n1=n0+16;
        stc8(&P.logits[(size_t)m3row*VC+n1],   packf2(ac1[0]+bo1[0],ac1[1]+bo1[1]));
        stc8(&P.logits[(size_t)m3row*VC+n1+2], packf2(ac1[2]+bo1[2],ac1[3]+bo1[3]));
      }
    }
    gbar(P.bar,bid,(unsigned)(4*t+3));
    // ---- stage4: log-softmax + argmax (block = batch row) ----
    {
      const int b=bid;
#pragma unroll
      for (int i=0;i<4;++i){
        unsigned long long qq=ldc8(&P.logits[(size_t)b*VC+tid*8+i*2]);
        u.sm.ls[tid*8+i*2]  =__uint_as_float((unsigned)qq);
        u.sm.ls[tid*8+i*2+1]=__uint_as_float((unsigned)(qq>>32));
      }
      __syncthreads();
      if (tid<V){
        float mx=-1e30f;
        for (int c=0;c<C;++c) mx=fmaxf(mx,u.sm.ls[c*V+tid]);
        float sum=0.f;
        for (int c=0;c<C;++c) sum+=expf(u.sm.ls[c*V+tid]-mx);
        float lse=mx+logf(sum);
        for (int c=0;c<C;++c) u.sm.ls[c*V+tid]-=lse;
      }
      __syncthreads();
      float bv=-1e30f; int bi=0;
#pragma unroll
      for (int i=0;i<VC/256;++i){
        int n=i*256+tid; float v=u.sm.ls[n];
        if (v>bv){bv=v;bi=n;}
      }
      u.sm.rv[tid]=bv; u.sm.ri[tid]=bi;
      __syncthreads();
      for (int s2=128;s2>0;s2>>=1){
        if (tid<s2){
          float v2=u.sm.rv[tid+s2]; int i2=u.sm.ri[tid+s2];
          if (v2>u.sm.rv[tid]||(v2==u.sm.rv[tid]&&i2<u.sm.ri[tid])){u.sm.rv[tid]=v2;u.sm.ri[tid]=i2;}
        }
        __syncthreads();
      }
      if (tid==0) stc4(&P.idxb[b],(unsigned)u.sm.ri[0]);
      float* dst=P.lsbuf+(size_t)(t&15)*BVC+(size_t)b*VC;
#pragma unroll
      for (int i=0;i<4;++i)
        stc8(&dst[tid*8+i*2], packf2(u.sm.ls[tid*8+i*2],u.sm.ls[tid*8+i*2+1]));
    }
    gbar(P.bar,bid,(unsigned)(4*t+4));
    // ---- flush 16 staged steps -> recon (coalesced 64B rows) ----
    if ((t&15)==15){
      const int t0=t-15;
      const size_t e0=((size_t)bid*256+tid)*8;
#pragma unroll
      for (int pe=0;pe<4;++pe){
        float va[16],vb[16];
#pragma unroll
        for (int j2=0;j2<16;++j2){
          unsigned long long qq=ldc8(&P.lsbuf[(size_t)j2*BVC+e0+pe*2]);
          va[j2]=__uint_as_float((unsigned)qq); vb[j2]=__uint_as_float((unsigned)(qq>>32));
        }
        float* d0=&P.recon[(e0+pe*2)*NSTEP+t0];
        float* d1=&P.recon[(e0+pe*2+1)*NSTEP+t0];
#pragma unroll
        for (int k=0;k<16;++k){ d0[k]=va[k]; d1[k]=vb[k]; }
      }
    }
  }
}

// ---------------- host orchestration ----------------
extern "C" void kernel_launch(void* const* d_in, const int* in_sizes, int n_in,
                              void* d_out, int out_size, void* d_ws, size_t ws_size,
                              hipStream_t stream) {
  const float* x        = (const float*)d_in[0];
  const float* noise    = (const float*)d_in[1];
  const float* gruf_Wih = (const float*)d_in[2];
  const float* gruf_Whh = (const float*)d_in[3];
  const float* gruf_bih = (const float*)d_in[4];
  const float* gruf_bhh = (const float*)d_in[5];
  const float* grub_Wih = (const float*)d_in[6];
  const float* grub_Whh = (const float*)d_in[7];
  const float* grub_bih = (const float*)d_in[8];
  const float* grub_bhh = (const float*)d_in[9];
  const float* Wmu      = (const float*)d_in[10];
  const float* bmu      = (const float*)d_in[11];
  const float* Wvar     = (const float*)d_in[12];
  const float* bvar     = (const float*)d_in[13];
  const float* Winit    = (const float*)d_in[14];
  const float* binit    = (const float*)d_in[15];
  const float* c1_Wih   = (const float*)d_in[16];
  const float* c1_Whh   = (const float*)d_in[17];
  const float* c1_bih   = (const float*)d_in[18];
  const float* c1_bhh   = (const float*)d_in[19];
  const float* c2_Wih   = (const float*)d_in[20];
  const float* c2_Whh   = (const float*)d_in[21];
  const float* c2_bih   = (const float*)d_in[22];
  const float* c2_bhh   = (const float*)d_in[23];
  const float* Wout     = (const float*)d_in[24];
  const float* bout     = (const float*)d_in[25];

  float* omu = (float*)d_out;
  float* ovar = omu + B*Z;
  float* oz = ovar + B*Z;
  float* orecon = oz + B*Z;

  char* p = (char*)d_ws;
  auto carve = [&](size_t bytes){ char* r = p; p += (bytes+255)&~(size_t)255; return r; };
  unsigned short* wihf_b  = (unsigned short*)carve((size_t)G3*V*2);
  unsigned short* whhf_b  = (unsigned short*)carve((size_t)G3*H*2);
  unsigned short* wihb_b  = (unsigned short*)carve((size_t)G3*V*2);
  unsigned short* whhb_b  = (unsigned short*)carve((size_t)G3*H*2);
  unsigned short* wc1hh_b = (unsigned short*)carve((size_t)G3*H*2);
  unsigned short* wc2ih_b = (unsigned short*)carve((size_t)G3*H*2);
  unsigned short* wc2hh_b = (unsigned short*)carve((size_t)G3*H*2);
  unsigned short* wout_b  = (unsigned short*)carve((size_t)VC*H*2);
  unsigned short* xtb     = (unsigned short*)carve((size_t)S*B*V*2);
  unsigned short* hf0     = (unsigned short*)carve((size_t)B*H*2);
  unsigned short* hf1     = (unsigned short*)carve((size_t)B*H*2);
  unsigned short* hb0     = (unsigned short*)carve((size_t)B*H*2);
  unsigned short* hb1     = (unsigned short*)carve((size_t)B*H*2);
  unsigned short* h1b0    = (unsigned short*)carve((size_t)B*H*2);
  unsigned short* h1b1    = (unsigned short*)carve((size_t)B*H*2);
  unsigned short* h2b0    = (unsigned short*)carve((size_t)B*H*2);
  unsigned short* h2b1    = (unsigned short*)carve((size_t)B*H*2);
  float* WT     = (float*)carve((size_t)VC*G3*4);
  float* zpart  = (float*)carve((size_t)B*G3*4);
  float* hf     = (float*)carve((size_t)B*H*4);
  float* hb     = (float*)carve((size_t)B*H*4);
  float* h1f    = (float*)carve((size_t)B*H*4);
  float* zws    = (float*)carve((size_t)B*Z*4);
  float* logits = (float*)carve((size_t)B*VC*4);
  float* lsbuf  = (float*)carve((size_t)16*BVC*4);
  int* idxb     = (int*)carve((size_t)B*4);
  unsigned* barE= (unsigned*)carve(16384);
  unsigned* barD= (unsigned*)carve(16384);

  dim3 blk(256);
  auto cvt=[&](const float* s, unsigned short* d, int n){
    int nb=(n+255)/256; if (nb>2048) nb=2048;
    k_cvt<<<nb,blk,0,stream>>>(s,d,n);
  };
  cvt(gruf_Wih,wihf_b,G3*V);
  cvt(gruf_Whh,whhf_b,G3*H);
  cvt(grub_Wih,wihb_b,G3*V);
  cvt(grub_Whh,whhb_b,G3*H);
  cvt(c1_Whh,wc1hh_b,G3*H);
  cvt(c2_Wih,wc2ih_b,G3*H);
  cvt(c2_Whh,wc2hh_b,G3*H);
  cvt(Wout,wout_b,VC*H);
  k_xt<<<dim3(S/32,(B*V)/32),dim3(32,8),0,stream>>>(x,xtb);
  k_wt<<<dim3(VC/32,G3/32),dim3(32,8),0,stream>>>(c1_Wih,WT);
  hipMemsetAsync(hf0,0,(size_t)B*H*2,stream);
  hipMemsetAsync(hb0,0,(size_t)B*H*2,stream);
  hipMemsetAsync(barE,0,16384,stream);
  hipMemsetAsync(barD,0,16384,stream);

  EncP ep;
  ep.xtb=xtb; ep.wihf=wihf_b; ep.whhf=whhf_b; ep.wihb=wihb_b; ep.whhb=whhb_b;
  ep.bihf=gruf_bih; ep.bhhf=gruf_bhh; ep.bihb=grub_bih; ep.bhhb=grub_bhh;
  ep.hf0=hf0; ep.hf1=hf1; ep.hb0=hb0; ep.hb1=hb1;
  ep.hf=hf; ep.hb=hb; ep.bar=barE;
  k_enc<<<256,blk,0,stream>>>(ep);

  k_mu_var_z<<<B,blk,0,stream>>>(hf,hb,Wmu,bmu,Wvar,bvar,noise,omu,ovar,oz,zws);
  k_zpart<<<B*G3/256,blk,0,stream>>>(zws,c1_Wih,c1_bih,zpart);
  k_h1init<<<B*H/256,blk,0,stream>>>(zws,Winit,binit,h1f,h1b0,idxb);

  DecP dp;
  dp.h1b0=h1b0; dp.h1b1=h1b1; dp.h2b0=h2b0; dp.h2b1=h2b1;
  dp.w1hh=wc1hh_b; dp.w2ih=wc2ih_b; dp.w2hh=wc2hh_b; dp.wout=wout_b;
  dp.bhh1=c1_bhh; dp.bih2=c2_bih; dp.bhh2=c2_bhh; dp.bout=bout;
  dp.zpart=zpart; dp.WT=WT; dp.h1f=h1f;
  dp.logits=logits; dp.lsbuf=lsbuf; dp.recon=orecon;
  dp.idxb=idxb; dp.bar=barD;
  k_dec<<<256,blk,0,stream>>>(dp);
}